// Round 6
// baseline (297.111 us; speedup 1.0000x reference)
//
#include <hip/hip_runtime.h>
#include <hip/hip_bf16.h>
#include <cstdint>
#include <cstddef>

constexpr int Bn = 8;
constexpr int Nn = 2048;
constexpr int Dn = 128;

typedef __bf16 bf16x8 __attribute__((ext_vector_type(8)));
typedef float f32x4 __attribute__((ext_vector_type(4)));

// -----------------------------------------------------------------------------
// Kernel 1 (unchanged): h = x@W (fp32), s1 = h@a1, s2 = h@a2, hT bf16 [B][D][N].
// -----------------------------------------------------------------------------
__global__ __launch_bounds__(256) void gat_k1(
    const float* __restrict__ x, const float* __restrict__ W,
    const float* __restrict__ a_vec,
    __bf16* __restrict__ hT, float* __restrict__ s1, float* __restrict__ s2) {
  __shared__ __align__(16) float Wl[64 * 144];  // [k][c-swizzled], 36.9KB
  __shared__ __align__(16) float xL[32 * 132];  // [r][k], 16.9KB

  const int t = threadIdx.x;
  const int r0 = blockIdx.x * 32;
  const int b = r0 >> 11;
  const int n0 = r0 & (Nn - 1);
  const int rp = (t >> 4) << 1;                 // row pair base 0..30
  const int c0 = (t & 15) << 3;                 // 0..120
  const int c0p = c0 + ((c0 >> 5) << 2);        // pad 4 dwords every 32

  float acc[2][8];
#pragma unroll
  for (int r = 0; r < 2; ++r)
#pragma unroll
    for (int c = 0; c < 8; ++c) acc[r][c] = 0.f;

  // stage xL: 32x128 fp32
#pragma unroll
  for (int it = 0; it < 4; ++it) {
    int idx = t + (it << 8);
    int rr = idx >> 5, kc = (idx & 31) << 2;
    *(float4*)(xL + rr * 132 + kc) = *(const float4*)(x + (size_t)(r0 + rr) * Dn + kc);
  }

  for (int ph = 0; ph < 2; ++ph) {
    if (ph) __syncthreads();  // phase-0 readers done before restage
#pragma unroll
    for (int it = 0; it < 8; ++it) {
      int idx = t + (it << 8);
      int kk = idx >> 5, c4 = (idx & 31) << 2;
      int dsto = kk * 144 + c4 + ((c4 >> 5) << 2);
      *(float4*)(Wl + dsto) = *(const float4*)(W + (size_t)((ph << 6) + kk) * Dn + c4);
    }
    __syncthreads();
    const float* xrow = xL + rp * 132 + (ph << 6);
    for (int k = 0; k < 64; ++k) {
      float xa0 = xrow[k];
      float xa1 = xrow[132 + k];
      float4 w0 = *(const float4*)(Wl + k * 144 + c0p);
      float4 w1 = *(const float4*)(Wl + k * 144 + c0p + 4);
      float ws[8] = {w0.x, w0.y, w0.z, w0.w, w1.x, w1.y, w1.z, w1.w};
#pragma unroll
      for (int c = 0; c < 8; ++c) {
        acc[0][c] = fmaf(xa0, ws[c], acc[0][c]);
        acc[1][c] = fmaf(xa1, ws[c], acc[1][c]);
      }
    }
  }

  // s1/s2: partial dots over my 8 cols, reduce across 16 col-groups (lanes&15)
  float q1[2] = {0.f, 0.f}, q2[2] = {0.f, 0.f};
#pragma unroll
  for (int c = 0; c < 8; ++c) {
    float a1c = a_vec[c0 + c];
    float a2c = a_vec[Dn + c0 + c];
    q1[0] = fmaf(acc[0][c], a1c, q1[0]);
    q1[1] = fmaf(acc[1][c], a1c, q1[1]);
    q2[0] = fmaf(acc[0][c], a2c, q2[0]);
    q2[1] = fmaf(acc[1][c], a2c, q2[1]);
  }
#pragma unroll
  for (int d = 1; d < 16; d <<= 1) {
    q1[0] += __shfl_xor(q1[0], d);
    q1[1] += __shfl_xor(q1[1], d);
    q2[0] += __shfl_xor(q2[0], d);
    q2[1] += __shfl_xor(q2[1], d);
  }
  if ((t & 15) == 0) {
    s1[b * Nn + n0 + rp] = q1[0];
    s1[b * Nn + n0 + rp + 1] = q1[1];
    s2[b * Nn + n0 + rp] = q2[0];
    s2[b * Nn + n0 + rp + 1] = q2[1];
  }

  // hT store: rows rp/rp+1 are adjacent n -> pack 2 bf16 per u32
#pragma unroll
  for (int c = 0; c < 8; ++c) {
    union { __bf16 h[2]; uint32_t u; } pk;
    pk.h[0] = (__bf16)acc[0][c];
    pk.h[1] = (__bf16)acc[1][c];
    *(uint32_t*)(hT + (size_t)(b * Dn + c0 + c) * Nn + n0 + rp) = pk.u;
  }
}

// -----------------------------------------------------------------------------
// Kernel A: alpha only. 1024 blocks x 256 thr, 16 i-rows/block, 16 thr/row.
// Pass-1: denominator + adj-mask capture (4 named VGPR words, 128 bits).
// Stream: pure [sj LDS read, 4 exp, NT float4 store] loop. ONE barrier total
// (sj staging); il stays in-register (the lanes that reduce l also use it).
// -----------------------------------------------------------------------------
__global__ __launch_bounds__(256) void gat_kA(
    const int* __restrict__ adj, const float* __restrict__ s1,
    const float* __restrict__ s2, float* __restrict__ alpha) {
  __shared__ __align__(16) float sj[Nn];  // 8 KB
  __shared__ float siv[16];

  const int t = threadIdx.x;
  const int b = blockIdx.x >> 7;
  const int i0 = (blockIdx.x & 127) << 4;
  const int row = t >> 4, sub = t & 15;

  *(float4*)(sj + (t << 3)) = *(const float4*)(s2 + b * Nn + (t << 3));
  *(float4*)(sj + (t << 3) + 4) = *(const float4*)(s2 + b * Nn + (t << 3) + 4);
  if (t < 16) siv[t] = s1[b * Nn + i0 + t];
  __syncthreads();

  const int i = i0 + row;
  const int* __restrict__ adjrow = adj + (size_t)i * Nn;
  const float si = siv[row];

  // pass 1: l = sum_j mask*exp(lrelu(si+sj)); mask bits -> mb0..mb3 (named)
  float l = 0.f;
  uint32_t mb0 = 0, mb1 = 0, mb2 = 0, mb3 = 0;
#define PASS1_G(G, MW)                                                        \
  {                                                                           \
    _Pragma("unroll")                                                         \
    for (int u = 0; u < 8; ++u) {                                             \
      int j = (((G) << 3) + u) * 64 + (sub << 2);                             \
      int4 am = *(const int4*)(adjrow + j);                                   \
      float4 sv = *(const float4*)(sj + j);                                   \
      float e0 = si + sv.x; e0 = fmaxf(e0, 0.2f * e0);                        \
      float e1 = si + sv.y; e1 = fmaxf(e1, 0.2f * e1);                        \
      float e2 = si + sv.z; e2 = fmaxf(e2, 0.2f * e2);                        \
      float e3 = si + sv.w; e3 = fmaxf(e3, 0.2f * e3);                        \
      l += (am.x > 0) ? __expf(e0) : 0.f;                                     \
      l += (am.y > 0) ? __expf(e1) : 0.f;                                     \
      l += (am.z > 0) ? __expf(e2) : 0.f;                                     \
      l += (am.w > 0) ? __expf(e3) : 0.f;                                     \
      uint32_t mbt = (am.x > 0 ? 1u : 0u) | (am.y > 0 ? 2u : 0u) |            \
                     (am.z > 0 ? 4u : 0u) | (am.w > 0 ? 8u : 0u);             \
      MW |= mbt << (u << 2);                                                  \
    }                                                                         \
  }
  PASS1_G(0, mb0)
  PASS1_G(1, mb1)
  PASS1_G(2, mb2)
  PASS1_G(3, mb3)
#undef PASS1_G

  // reduce across the 16 lanes of this row; il stays in-register (no barrier)
  l += __shfl_xor(l, 1);
  l += __shfl_xor(l, 2);
  l += __shfl_xor(l, 4);
  l += __shfl_xor(l, 8);
  const float il = 1.f / l;

  float* __restrict__ arow = alpha + ((size_t)(b * Nn + i) << 11);

  // streaming alpha: no barriers, no LDS writes, independent iterations
#pragma unroll
  for (int k = 0; k < 32; ++k) {
    int j = (k << 6) + (sub << 2);
    float4 sv = *(const float4*)(sj + j);
    uint32_t mw = (k & 16) ? ((k & 8) ? mb3 : mb2) : ((k & 8) ? mb1 : mb0);
    int sh = (k & 7) << 2;
    float e0 = si + sv.x; e0 = fmaxf(e0, 0.2f * e0);
    float e1 = si + sv.y; e1 = fmaxf(e1, 0.2f * e1);
    float e2 = si + sv.z; e2 = fmaxf(e2, 0.2f * e2);
    float e3 = si + sv.w; e3 = fmaxf(e3, 0.2f * e3);
    float a0 = ((mw >> (sh + 0)) & 1u) ? __expf(e0) * il : 0.f;
    float a1 = ((mw >> (sh + 1)) & 1u) ? __expf(e1) * il : 0.f;
    float a2 = ((mw >> (sh + 2)) & 1u) ? __expf(e2) * il : 0.f;
    float a3 = ((mw >> (sh + 3)) & 1u) ? __expf(e3) * il : 0.f;
    f32x4 av = {a0, a1, a2, a3};
    __builtin_nontemporal_store(av, (f32x4*)(arow + j));
  }
}

// -----------------------------------------------------------------------------
// Kernel B: out = alpha @ h, pure register GEMM. 512 blocks x 256 thr.
// Per batch: M=2048(i) x N=128(d), K=2048(j). Block = 32 i-rows; wave w:
// i-half (w&1)*16, d-half (w>>1)*64 (4 d-tiles of 16). A = alpha fp32 rows
// (k-contiguous, cvt->bf16 in flight); B = hT rows (k-contiguous). No LDS,
// no barriers; waves fully independent; latency hidden by unroll + 8 waves/CU.
// -----------------------------------------------------------------------------
__global__ __launch_bounds__(256) void gat_kB(
    const float* __restrict__ alpha, const __bf16* __restrict__ hT,
    float* __restrict__ out) {
  const int t = threadIdx.x;
  const int b = blockIdx.x >> 6;
  const int m0 = (blockIdx.x & 63) << 5;
  const int w = t >> 6, lane = t & 63;
  const int q16 = lane >> 4, m16 = lane & 15;  // q16: k-chunk 0..3, m16: row
  const int iw = (w & 1) << 4;
  const int d0w = (w >> 1) << 6;

  const float* __restrict__ arow =
      alpha + ((size_t)(b * Nn + m0 + iw + m16) << 11) + (q16 << 3);
  const __bf16* __restrict__ hb = hT + (size_t)b * Dn * Nn + (q16 << 3);
  const __bf16* __restrict__ hb0 = hb + (size_t)(d0w + 0 * 16 + m16) * Nn;
  const __bf16* __restrict__ hb1 = hb + (size_t)(d0w + 1 * 16 + m16) * Nn;
  const __bf16* __restrict__ hb2 = hb + (size_t)(d0w + 2 * 16 + m16) * Nn;
  const __bf16* __restrict__ hb3 = hb + (size_t)(d0w + 3 * 16 + m16) * Nn;

  f32x4 acc0 = {0.f, 0.f, 0.f, 0.f}, acc1 = {0.f, 0.f, 0.f, 0.f};
  f32x4 acc2 = {0.f, 0.f, 0.f, 0.f}, acc3 = {0.f, 0.f, 0.f, 0.f};

#pragma unroll 4
  for (int k0 = 0; k0 < Nn; k0 += 32) {
    float4 alo = *(const float4*)(arow + k0);
    float4 ahi = *(const float4*)(arow + k0 + 4);
    bf16x8 b0 = *(const bf16x8*)(hb0 + k0);
    bf16x8 b1 = *(const bf16x8*)(hb1 + k0);
    bf16x8 b2 = *(const bf16x8*)(hb2 + k0);
    bf16x8 b3 = *(const bf16x8*)(hb3 + k0);
    bf16x8 af;
    af[0] = (__bf16)alo.x; af[1] = (__bf16)alo.y;
    af[2] = (__bf16)alo.z; af[3] = (__bf16)alo.w;
    af[4] = (__bf16)ahi.x; af[5] = (__bf16)ahi.y;
    af[6] = (__bf16)ahi.z; af[7] = (__bf16)ahi.w;
    acc0 = __builtin_amdgcn_mfma_f32_16x16x32_bf16(af, b0, acc0, 0, 0, 0);
    acc1 = __builtin_amdgcn_mfma_f32_16x16x32_bf16(af, b1, acc1, 0, 0, 0);
    acc2 = __builtin_amdgcn_mfma_f32_16x16x32_bf16(af, b2, acc2, 0, 0, 0);
    acc3 = __builtin_amdgcn_mfma_f32_16x16x32_bf16(af, b3, acc3, 0, 0, 0);
  }

  // epilogue: D row=(q16*4+r) -> i within 16, col=m16 -> d within tile
  const int ibase = m0 + iw + (q16 << 2);
#pragma unroll
  for (int dt = 0; dt < 4; ++dt) {
    f32x4 a = (dt == 0) ? acc0 : (dt == 1) ? acc1 : (dt == 2) ? acc2 : acc3;
    int d = d0w + (dt << 4) + m16;
#pragma unroll
    for (int r = 0; r < 4; ++r) {
      out[((size_t)(b * Nn + ibase + r) << 7) + d] = a[r];
    }
  }
}

extern "C" void kernel_launch(void* const* d_in, const int* in_sizes, int n_in,
                              void* d_out, int out_size, void* d_ws, size_t ws_size,
                              hipStream_t stream) {
  const float* x = (const float*)d_in[0];
  const int* adj = (const int*)d_in[1];
  const float* W = (const float*)d_in[2];
  const float* a_vec = (const float*)d_in[3];

  float* out = (float*)d_out;
  float* alpha = out + (size_t)Bn * Nn * Dn;  // outputs concatenated: (out, alpha)

  char* ws = (char*)d_ws;
  __bf16* hT = (__bf16*)ws;                               // B*D*N bf16 = 4 MiB
  float* s1 = (float*)(ws + (size_t)Bn * Dn * Nn * 2);    // B*N fp32
  float* s2 = s1 + (size_t)Bn * Nn;                       // B*N fp32

  gat_k1<<<512, 256, 0, stream>>>(x, W, a_vec, hT, s1, s2);
  gat_kA<<<1024, 256, 0, stream>>>(adj, s1, s2, alpha);
  gat_kB<<<512, 256, 0, stream>>>(alpha, hT, out);
}

// Round 7
// 246.657 us; speedup vs baseline: 1.2046x; 1.2046x over previous
//
#include <hip/hip_runtime.h>
#include <hip/hip_bf16.h>
#include <cstdint>
#include <cstddef>

constexpr int Bn = 8;
constexpr int Nn = 2048;
constexpr int Dn = 128;

typedef __bf16 bf16x8 __attribute__((ext_vector_type(8)));
typedef float f32x4 __attribute__((ext_vector_type(4)));

// -----------------------------------------------------------------------------
// Kernel 1 (unchanged): h = x@W (fp32), s1 = h@a1, s2 = h@a2, hT bf16 [B][D][N].
// -----------------------------------------------------------------------------
__global__ __launch_bounds__(256) void gat_k1(
    const float* __restrict__ x, const float* __restrict__ W,
    const float* __restrict__ a_vec,
    __bf16* __restrict__ hT, float* __restrict__ s1, float* __restrict__ s2) {
  __shared__ __align__(16) float Wl[64 * 144];  // [k][c-swizzled], 36.9KB
  __shared__ __align__(16) float xL[32 * 132];  // [r][k], 16.9KB

  const int t = threadIdx.x;
  const int r0 = blockIdx.x * 32;
  const int b = r0 >> 11;
  const int n0 = r0 & (Nn - 1);
  const int rp = (t >> 4) << 1;                 // row pair base 0..30
  const int c0 = (t & 15) << 3;                 // 0..120
  const int c0p = c0 + ((c0 >> 5) << 2);        // pad 4 dwords every 32

  float acc[2][8];
#pragma unroll
  for (int r = 0; r < 2; ++r)
#pragma unroll
    for (int c = 0; c < 8; ++c) acc[r][c] = 0.f;

  // stage xL: 32x128 fp32
#pragma unroll
  for (int it = 0; it < 4; ++it) {
    int idx = t + (it << 8);
    int rr = idx >> 5, kc = (idx & 31) << 2;
    *(float4*)(xL + rr * 132 + kc) = *(const float4*)(x + (size_t)(r0 + rr) * Dn + kc);
  }

  for (int ph = 0; ph < 2; ++ph) {
    if (ph) __syncthreads();  // phase-0 readers done before restage
#pragma unroll
    for (int it = 0; it < 8; ++it) {
      int idx = t + (it << 8);
      int kk = idx >> 5, c4 = (idx & 31) << 2;
      int dsto = kk * 144 + c4 + ((c4 >> 5) << 2);
      *(float4*)(Wl + dsto) = *(const float4*)(W + (size_t)((ph << 6) + kk) * Dn + c4);
    }
    __syncthreads();
    const float* xrow = xL + rp * 132 + (ph << 6);
    for (int k = 0; k < 64; ++k) {
      float xa0 = xrow[k];
      float xa1 = xrow[132 + k];
      float4 w0 = *(const float4*)(Wl + k * 144 + c0p);
      float4 w1 = *(const float4*)(Wl + k * 144 + c0p + 4);
      float ws[8] = {w0.x, w0.y, w0.z, w0.w, w1.x, w1.y, w1.z, w1.w};
#pragma unroll
      for (int c = 0; c < 8; ++c) {
        acc[0][c] = fmaf(xa0, ws[c], acc[0][c]);
        acc[1][c] = fmaf(xa1, ws[c], acc[1][c]);
      }
    }
  }

  // s1/s2: partial dots over my 8 cols, reduce across 16 col-groups (lanes&15)
  float q1[2] = {0.f, 0.f}, q2[2] = {0.f, 0.f};
#pragma unroll
  for (int c = 0; c < 8; ++c) {
    float a1c = a_vec[c0 + c];
    float a2c = a_vec[Dn + c0 + c];
    q1[0] = fmaf(acc[0][c], a1c, q1[0]);
    q1[1] = fmaf(acc[1][c], a1c, q1[1]);
    q2[0] = fmaf(acc[0][c], a2c, q2[0]);
    q2[1] = fmaf(acc[1][c], a2c, q2[1]);
  }
#pragma unroll
  for (int d = 1; d < 16; d <<= 1) {
    q1[0] += __shfl_xor(q1[0], d);
    q1[1] += __shfl_xor(q1[1], d);
    q2[0] += __shfl_xor(q2[0], d);
    q2[1] += __shfl_xor(q2[1], d);
  }
  if ((t & 15) == 0) {
    s1[b * Nn + n0 + rp] = q1[0];
    s1[b * Nn + n0 + rp + 1] = q1[1];
    s2[b * Nn + n0 + rp] = q2[0];
    s2[b * Nn + n0 + rp + 1] = q2[1];
  }

  // hT store: rows rp/rp+1 are adjacent n -> pack 2 bf16 per u32
#pragma unroll
  for (int c = 0; c < 8; ++c) {
    union { __bf16 h[2]; uint32_t u; } pk;
    pk.h[0] = (__bf16)acc[0][c];
    pk.h[1] = (__bf16)acc[1][c];
    *(uint32_t*)(hT + (size_t)(b * Dn + c0 + c) * Nn + n0 + rp) = pk.u;
  }
}

// -----------------------------------------------------------------------------
// Kernel 2: barrier-free fused lanes. 1024 blocks x 256 thr (4 waves), ALL
// blocks resident (4/CU). Wave jq = j-quarter [512*jq, 512*jq+512).
// Lane (m16,q16) OWNS A-frag row i0+m16, k-slice q16*8: computes its 8 alphas
// in-register (adj+sj -> exp -> bf16), stores them NT, feeds MFMA directly.
// NO LDS P-exchange, NO barrier in the main loop. Epilogue: 4-way fp32 acc
// reduce via LDS (aliases sj), 3 lgkm-only barriers total.
// -----------------------------------------------------------------------------
__global__ __launch_bounds__(256, 4) void gat_k2(
    const int* __restrict__ adj, const __bf16* __restrict__ hT,
    const float* __restrict__ s1, const float* __restrict__ s2,
    float* __restrict__ out, float* __restrict__ alpha) {
  __shared__ __align__(16) float accL[4 * 16 * 128];  // 32KB; first 8KB = sj
  __shared__ float lq[4][16];
  float* const sj = accL;  // sj alias: dead before accL is written (barriered)

  const int t = threadIdx.x;
  const int b = blockIdx.x >> 7;
  const int i0 = (blockIdx.x & 127) << 4;
  const int jq = t >> 6, lane = t & 63;
  const int q16 = lane >> 4, m16 = lane & 15;
  const int jo = (jq << 9) + (q16 << 3);  // lane's absolute j base

  // stage sj = s2 row of batch b (8 floats/thread)
  *(float4*)(sj + (t << 3)) = *(const float4*)(s2 + b * Nn + (t << 3));
  *(float4*)(sj + (t << 3) + 4) = *(const float4*)(s2 + b * Nn + (t << 3) + 4);
  asm volatile("s_waitcnt lgkmcnt(0)\n\ts_barrier" ::: "memory");

  const int i = i0 + m16;
  const float si = s1[b * Nn + i];
  const int* __restrict__ adjrow = adj + (size_t)i * Nn + jo;
  const float* __restrict__ sjl = sj + jo;

  // Phase A: partial denominator over my stripe of the j-quarter
  float l = 0.f;
#pragma unroll 4
  for (int jt = 0; jt < 16; ++jt) {
    int o = jt << 5;
    int4 am0 = *(const int4*)(adjrow + o);
    int4 am1 = *(const int4*)(adjrow + o + 4);
    float4 v0 = *(const float4*)(sjl + o);
    float4 v1 = *(const float4*)(sjl + o + 4);
    float e0 = si + v0.x; e0 = fmaxf(e0, 0.2f * e0);
    float e1 = si + v0.y; e1 = fmaxf(e1, 0.2f * e1);
    float e2 = si + v0.z; e2 = fmaxf(e2, 0.2f * e2);
    float e3 = si + v0.w; e3 = fmaxf(e3, 0.2f * e3);
    float e4 = si + v1.x; e4 = fmaxf(e4, 0.2f * e4);
    float e5 = si + v1.y; e5 = fmaxf(e5, 0.2f * e5);
    float e6 = si + v1.z; e6 = fmaxf(e6, 0.2f * e6);
    float e7 = si + v1.w; e7 = fmaxf(e7, 0.2f * e7);
    l += (am0.x > 0) ? __expf(e0) : 0.f;
    l += (am0.y > 0) ? __expf(e1) : 0.f;
    l += (am0.z > 0) ? __expf(e2) : 0.f;
    l += (am0.w > 0) ? __expf(e3) : 0.f;
    l += (am1.x > 0) ? __expf(e4) : 0.f;
    l += (am1.y > 0) ? __expf(e5) : 0.f;
    l += (am1.z > 0) ? __expf(e6) : 0.f;
    l += (am1.w > 0) ? __expf(e7) : 0.f;
  }
  // combine the 4 q16-stripes (lanes m16, +16, +32, +48)
  l += __shfl_xor(l, 16);
  l += __shfl_xor(l, 32);
  if (q16 == 0) lq[jq][m16] = l;
  asm volatile("s_waitcnt lgkmcnt(0)\n\ts_barrier" ::: "memory");
  const float il = 1.f / (lq[0][m16] + lq[1][m16] + lq[2][m16] + lq[3][m16]);

  // Phase B: 16 windows, barrier-free. Each lane: 8 alphas -> NT store +
  // A-frag; 8 B-loads (L2-hot hT); 8 MFMA.
  f32x4 acc0 = {0.f, 0.f, 0.f, 0.f}, acc1 = {0.f, 0.f, 0.f, 0.f};
  f32x4 acc2 = {0.f, 0.f, 0.f, 0.f}, acc3 = {0.f, 0.f, 0.f, 0.f};
  f32x4 acc4 = {0.f, 0.f, 0.f, 0.f}, acc5 = {0.f, 0.f, 0.f, 0.f};
  f32x4 acc6 = {0.f, 0.f, 0.f, 0.f}, acc7 = {0.f, 0.f, 0.f, 0.f};
  float* __restrict__ arow = alpha + ((size_t)(b * Nn + i) << 11) + jo;
  const __bf16* __restrict__ hrow = hT + (size_t)b * Dn * Nn + (size_t)m16 * Nn + jo;

#pragma unroll 2
  for (int jt = 0; jt < 16; ++jt) {
    int o = jt << 5;
    int4 am0 = *(const int4*)(adjrow + o);
    int4 am1 = *(const int4*)(adjrow + o + 4);
    float4 v0 = *(const float4*)(sjl + o);
    float4 v1 = *(const float4*)(sjl + o + 4);
    float e0 = si + v0.x; e0 = fmaxf(e0, 0.2f * e0);
    float e1 = si + v0.y; e1 = fmaxf(e1, 0.2f * e1);
    float e2 = si + v0.z; e2 = fmaxf(e2, 0.2f * e2);
    float e3 = si + v0.w; e3 = fmaxf(e3, 0.2f * e3);
    float e4 = si + v1.x; e4 = fmaxf(e4, 0.2f * e4);
    float e5 = si + v1.y; e5 = fmaxf(e5, 0.2f * e5);
    float e6 = si + v1.z; e6 = fmaxf(e6, 0.2f * e6);
    float e7 = si + v1.w; e7 = fmaxf(e7, 0.2f * e7);
    float a0 = (am0.x > 0) ? __expf(e0) * il : 0.f;
    float a1 = (am0.y > 0) ? __expf(e1) * il : 0.f;
    float a2 = (am0.z > 0) ? __expf(e2) * il : 0.f;
    float a3 = (am0.w > 0) ? __expf(e3) * il : 0.f;
    float a4 = (am1.x > 0) ? __expf(e4) * il : 0.f;
    float a5 = (am1.y > 0) ? __expf(e5) * il : 0.f;
    float a6 = (am1.z > 0) ? __expf(e6) * il : 0.f;
    float a7 = (am1.w > 0) ? __expf(e7) * il : 0.f;
    f32x4 w0 = {a0, a1, a2, a3};
    f32x4 w1 = {a4, a5, a6, a7};
    __builtin_nontemporal_store(w0, (f32x4*)(arow + o));
    __builtin_nontemporal_store(w1, (f32x4*)(arow + o + 4));
    bf16x8 af;
    af[0] = (__bf16)a0; af[1] = (__bf16)a1;
    af[2] = (__bf16)a2; af[3] = (__bf16)a3;
    af[4] = (__bf16)a4; af[5] = (__bf16)a5;
    af[6] = (__bf16)a6; af[7] = (__bf16)a7;
    const __bf16* hp = hrow + o;
#define MF(DT, A)                                                            \
  {                                                                          \
    bf16x8 bv = *(const bf16x8*)(hp + (size_t)(DT) * (16 * Nn));             \
    A = __builtin_amdgcn_mfma_f32_16x16x32_bf16(af, bv, A, 0, 0, 0);         \
  }
    MF(0, acc0) MF(1, acc1) MF(2, acc2) MF(3, acc3)
    MF(4, acc4) MF(5, acc5) MF(6, acc6) MF(7, acc7)
#undef MF
  }

  // Phase C: 4-way cross-wave acc reduce. accL aliases sj: barrier first
  // (lgkm-only; in-flight NT stores don't touch LDS).
  asm volatile("s_waitcnt lgkmcnt(0)\n\ts_barrier" ::: "memory");
#define WR(DT, A)                                                            \
  {                                                                          \
    _Pragma("unroll")                                                        \
    for (int r = 0; r < 4; ++r)                                              \
      accL[(jq << 11) + (((q16 << 2) + r) << 7) + ((DT) << 4) + m16] = A[r]; \
  }
  WR(0, acc0) WR(1, acc1) WR(2, acc2) WR(3, acc3)
  WR(4, acc4) WR(5, acc5) WR(6, acc6) WR(7, acc7)
#undef WR
  asm volatile("s_waitcnt lgkmcnt(0)\n\ts_barrier" ::: "memory");
  {
    const int row = t >> 4, dc = (t & 15) << 3;
    const float* p = accL + (row << 7) + dc;
    f32x4 u0 = *(const f32x4*)(p);
    f32x4 u1 = *(const f32x4*)(p + 4);
#pragma unroll
    for (int q = 1; q < 4; ++q) {
      u0 += *(const f32x4*)(p + (q << 11));
      u1 += *(const f32x4*)(p + (q << 11) + 4);
    }
    float* op = out + ((size_t)(b * Nn + i0 + row) << 7) + dc;
    __builtin_nontemporal_store(u0, (f32x4*)op);
    __builtin_nontemporal_store(u1, (f32x4*)(op + 4));
  }
}

extern "C" void kernel_launch(void* const* d_in, const int* in_sizes, int n_in,
                              void* d_out, int out_size, void* d_ws, size_t ws_size,
                              hipStream_t stream) {
  const float* x = (const float*)d_in[0];
  const int* adj = (const int*)d_in[1];
  const float* W = (const float*)d_in[2];
  const float* a_vec = (const float*)d_in[3];

  float* out = (float*)d_out;
  float* alpha = out + (size_t)Bn * Nn * Dn;  // outputs concatenated: (out, alpha)

  char* ws = (char*)d_ws;
  __bf16* hT = (__bf16*)ws;                               // B*D*N bf16 = 4 MiB
  float* s1 = (float*)(ws + (size_t)Bn * Dn * Nn * 2);    // B*N fp32
  float* s2 = s1 + (size_t)Bn * Nn;                       // B*N fp32

  gat_k1<<<512, 256, 0, stream>>>(x, W, a_vec, hT, s1, s2);
  gat_k2<<<1024, 256, 0, stream>>>(adj, hT, s1, s2, out, alpha);
}